// Round 9
// baseline (72.299 us; speedup 1.0000x reference)
//
#include <hip/hip_runtime.h>
#include <math.h>

// Tropical max/min-plus pseudo-matmul.
// out[b,u] = max_f(x[b,f] + w[f,u]) for u<128, min_f otherwise.
//
// R21: break the 1-block/CU phase-lock -- 2 INDEPENDENT blocks per CU.
// R20 post-mortem: x via LDS (R12), VMEM broadcast (R17/19), forced SMEM
// (R20) all land within 0.5us -> x delivery was never the bottleneck. The
// kernel sits at ~2x its hard VALU floor (402.6M lane-ops / 78.6T/s =
// 5.12us; adds and max3 both irreducible; v_pk_add_f32 rejected on paper:
// 157.3TF peak == scalar SIMD-32 rate, packing saves issue slots we don't
// need, not ALU cycles). Untested structural suspect: every prior round ran
// exactly 1 block/CU, so all waves on a SIMD are launch- and code-phase-
// locked -- they reach their per-step waits together and nothing covers.
// This round: 512-thr blocks (8 waves = 4 kslices x 2 halves, KW=128),
// BR=4, grid=512 -> 2 blocks/CU, 8 waves/SIMD, no inter-block barrier ->
// natural stagger; per-step VALU cover = 8 waves deep.
//   - x stays forced-SMEM (s_load_dwordx4, dbuf 2x16 SGPR): TA stays w-only
//     (~3.4us/CU); VMEM-x at 16 waves/CU would put TA over the VALU floor.
//   - SMEM is OOO -> lgkmcnt(0) only; SB(0)/wait/SB(0) fences (rule #18).
//   - VGPR ~45 -> waves_per_eu(8,8) 64-cap fits; LDS = real 16KB (small
//     LDS required for 2-block residency; budget now set by the attr).
//   - min/max split by wave half: no divergence, no sign math (epilogue
//     hh is wave-uniform too).
// Failure tell: kernel >40us in top-5 w/ VGPR_Count=64 -> 64-cap spilled,
// relax to waves_per_eu(4,8) next round.

#define FEAT  512
#define UNITS 256
#define BR    4            // rows per block
#define NW    8            // waves per block (4 k-slices x 2 halves)
#define KW    128          // k per wave
#define NS    (KW / 4)     // 32 steps, 4 k per step

typedef float f32x4 __attribute__((ext_vector_type(4)));

__device__ __forceinline__ float max3f(float a, float b, float c) {
    return fmaxf(fmaxf(a, b), c);   // v_max3_f32
}
__device__ __forceinline__ float min3f(float a, float b, float c) {
    return fminf(fminf(a, b), c);   // v_min3_f32
}

// one s_load_dwordx4 at compile-time byte offset OFF (template -> guaranteed imm)
template<int OFF>
__device__ __forceinline__ void sload1(const float* __restrict__ p, f32x4& d) {
    asm volatile("s_load_dwordx4 %0, %1, %2" : "=s"(d) : "s"(p), "i"(OFF));
}

// 4 s_load_dwordx4: x[row0+r][k0..k0+3], r=0..3 (byte offsets r*2048)
__device__ __forceinline__ void sload_xstep(const float* __restrict__ xp_s,
                                            f32x4* __restrict__ xb) {
    sload1<0 * 2048>(xp_s, xb[0]);
    sload1<1 * 2048>(xp_s, xb[1]);
    sload1<2 * 2048>(xp_s, xb[2]);
    sload1<3 * 2048>(xp_s, xb[3]);
}

__device__ __forceinline__ void smem_wait_fenced() {
    __builtin_amdgcn_sched_barrier(0);                 // pin cover-compute above
    asm volatile("s_waitcnt lgkmcnt(0)" ::: "memory"); // SMEM is OOO: only 0 valid
    __builtin_amdgcn_sched_barrier(0);                 // pin consumers below
}

// 4 dwordx2: w[k0+j][u0..u0+1] -- 64 lanes x 8B = 512B contiguous
__device__ __forceinline__ void load_wstep(const float* __restrict__ wp, int s,
                                           float2* __restrict__ wb) {
    #pragma unroll
    for (int j = 0; j < 4; ++j)
        wb[j] = *(const float2*)(wp + (size_t)(s * 4 + j) * UNITS);
}

// per step: 4 rows x (8 add + 4 max3/min3) = 48 VALU inst; x from SGPRs
// (v_add_f32 v,s,v -- one SGPR operand per instruction)
template<bool ISMAX>
__device__ __forceinline__ void compute_step(const f32x4* __restrict__ xb,
                                             const float2* __restrict__ wq,
                                             float2* __restrict__ acc) {
    #pragma unroll
    for (int r = 0; r < BR; ++r) {
        const f32x4 a = xb[r];
        const float t0x = a.x + wq[0].x, t0y = a.x + wq[0].y;
        const float t1x = a.y + wq[1].x, t1y = a.y + wq[1].y;
        const float t2x = a.z + wq[2].x, t2y = a.z + wq[2].y;
        const float t3x = a.w + wq[3].x, t3y = a.w + wq[3].y;
        float2 A = acc[r];
        if (ISMAX) {
            A.x = max3f(A.x, t0x, t1x);  A.x = max3f(A.x, t2x, t3x);
            A.y = max3f(A.y, t0y, t1y);  A.y = max3f(A.y, t2y, t3y);
        } else {
            A.x = min3f(A.x, t0x, t1x);  A.x = min3f(A.x, t2x, t3x);
            A.y = min3f(A.y, t0y, t1y);  A.y = min3f(A.y, t2y, t3y);
        }
        acc[r] = A;
    }
}

// software pipeline: x (SMEM) and w (VMEM) one step ahead; one SMEM batch
// outstanding at each wait
template<bool ISMAX>
__device__ __forceinline__ void main_loop(const float* __restrict__ xp,
                                          const float* __restrict__ wp,
                                          float2* __restrict__ acc) {
    f32x4  xA[BR], xB[BR];
    float2 wA[4], wB[4];
    sload_xstep(xp, xA);
    load_wstep(wp, 0, wA);
    smem_wait_fenced();                       // batch 0 ready
    #pragma unroll 1
    for (int s = 0; s < NS; s += 2) {
        sload_xstep(xp + (s + 1) * 4, xB);    // issue batch s+1
        load_wstep(wp, s + 1, wB);
        compute_step<ISMAX>(xA, wA, acc);     // covers batch s+1 latency
        smem_wait_fenced();                   // batch s+1 ready
        if (s + 2 < NS) {
            sload_xstep(xp + (s + 2) * 4, xA);
            load_wstep(wp, s + 2, wA);
        }
        compute_step<ISMAX>(xB, wB, acc);     // covers batch s+2 latency
        smem_wait_fenced();                   // batch s+2 ready (tail: no-op)
    }
}

__global__ __launch_bounds__(512)
__attribute__((amdgpu_waves_per_eu(8, 8)))
void tropical_kernel(const float* __restrict__ x,
                     const float* __restrict__ w,
                     float* __restrict__ out) {
    __shared__ float lds[NW * BR * 128];   // 16 KB real -- 2-block residency
    const int tid  = threadIdx.x;
    const int lane = tid & 63;
    const int wv   = __builtin_amdgcn_readfirstlane(tid >> 6);  // 0..7
    const int kslice = wv & 3;           // k origin index
    const int half   = wv >> 2;          // 0: max units 0-127, 1: min 128-255
    const int ks   = kslice * KW;
    const int u0   = lane * 2;           // 2 units per lane, contiguous
    const int row0 = blockIdx.x * BR;

    const float* xp = x + (size_t)row0 * FEAT + ks;          // uniform
    const float* wp = w + (size_t)ks * UNITS + half * 128 + u0;

    float2 acc[BR];
    const float init = half ? __builtin_inff() : -__builtin_inff();
    #pragma unroll
    for (int r = 0; r < BR; ++r)
        acc[r] = make_float2(init, init);

    if (half == 0) main_loop<true >(xp, wp, acc);
    else           main_loop<false>(xp, wp, acc);

    // ---- partials to LDS: wave wv -> slot wv, 128 units of its half ----
    #pragma unroll
    for (int r = 0; r < BR; ++r)
        *(float2*)&lds[(wv * BR + r) * 128 + u0] = acc[r];   // 512B/wave-row
    __syncthreads();   // the kernel's only barrier

    // ---- combine 4 k-slice partials; thread -> float2 of output ----
    const int r  = tid >> 7;             // 0..3
    const int j2 = tid & 127;
    const int hh = j2 >> 6;              // wave-uniform: 0=max half, 1=min half
    const int uo = (j2 & 63) * 2;        // unit offset within the half
    float2 v = *(const float2*)&lds[((hh * 4 + 0) * BR + r) * 128 + uo];
    #pragma unroll
    for (int j = 1; j < 4; ++j) {
        const float2 p = *(const float2*)&lds[((hh * 4 + j) * BR + r) * 128 + uo];
        if (hh == 0) { v.x = fmaxf(v.x, p.x); v.y = fmaxf(v.y, p.y); }
        else         { v.x = fminf(v.x, p.x); v.y = fminf(v.y, p.y); }
    }
    *(float2*)&out[(size_t)(row0 + r) * UNITS + hh * 128 + uo] = v;
}

extern "C" void kernel_launch(void* const* d_in, const int* in_sizes, int n_in,
                              void* d_out, int out_size, void* d_ws, size_t ws_size,
                              hipStream_t stream) {
    const float* x = (const float*)d_in[0];   // (2048, 512)
    const float* w = (const float*)d_in[1];   // (512, 256)
    float* out = (float*)d_out;               // (2048, 256)

    // 512 blocks x 8 waves = 2 independent blocks/CU, 8 waves/SIMD
    tropical_kernel<<<dim3(2048 / BR), dim3(512), 0, stream>>>(x, w, out);
}

// Round 11
// 71.535 us; speedup vs baseline: 1.0107x; 1.0107x over previous
//
#include <hip/hip_runtime.h>
#include <math.h>

// Tropical max/min-plus pseudo-matmul.
// out[b,u] = max_f(x[b,f] + w[f,u]) for u<128, min_f otherwise.
//
// R22 = R19 (best measured: 68.07) + w prefetch at ISSUE-DISTANCE 2.
// (Resubmit of R22 -- previous round's bench run died on container infra,
// no measurement was taken.)
// R21 post-mortem: 512 blocks doubled per-block w re-reads -> 256MB L2
// demand ~ 7.5us > VALU floor -> regression. Geometry reverted to R19
// (256 blocks x 16 waves, 1 block/CU, TLP=4).
// Theory for the stubborn ~2x-over-floor plateau (R12/R19/R20 all ~68.x
// with three different x-paths): the one never-varied mechanism is w
// pipeline depth = 1. Per step: VALU cover = 96 inst x 2cy = 192 cyc,
// but L2-hit latency ~200-300 cyc (m125) -> every step pays the
// uncovered remainder, and waves are phase-locked so TLP=4 doesn't
// decorrelate the stalls. 16 steps x ~300/192 ~= 1.5-1.7x floor ~= the
// observed ~10.5us kernel.
// Change (ONLY this): w double -> quad buffer W0..W3, loop unrolled x4
// (all buffer names compile-time static, rule #20), w(s+2) issued while
// computing step s -> 384 cyc cover > L2 latency. x path byte-identical
// to R19 (AS4 scalar copies, distance 1; x lines are L1/K$-resident so
// distance 1 suffices). VGPR: W 32 + acc 16 + addr ~ small; x in SGPRs
// -> far under the 128 budget of waves_per_eu(4,4).
// 96KB LDS belt kept (1 block/CU truth-telling to the allocator).

#define FEAT  512
#define UNITS 256
#define BR    8            // rows per block
#define NW    16           // waves per block (8 k-slices x 2 halves)
#define KW    64           // k per wave
#define NS    (KW / 4)     // 16 steps, 4 k per step
#define LDSZ  24576        // 96KB declared (occupancy belt); 64KB used

typedef __attribute__((address_space(4))) const float cfloat;

__device__ __forceinline__ float max3f(float a, float b, float c) {
    return fmaxf(fmaxf(a, b), c);   // v_max3_f32
}
__device__ __forceinline__ float min3f(float a, float b, float c) {
    return fminf(fminf(a, b), c);   // v_min3_f32
}

// 8 uniform 16B x-loads: x[row0+r][ks + s*4 .. +3] (scalar copies: AS4-safe)
__device__ __forceinline__ void load_xstep(cfloat* __restrict__ xp, int s,
                                           float4* __restrict__ xb) {
    #pragma unroll
    for (int r = 0; r < BR; ++r) {
        const int o = r * FEAT + s * 4;
        xb[r].x = xp[o + 0];
        xb[r].y = xp[o + 1];
        xb[r].z = xp[o + 2];
        xb[r].w = xp[o + 3];
    }
}

// 4 dwordx2: w[ks+s*4+j][u0..u0+1] -- 64 lanes x 8B = 512B contiguous
__device__ __forceinline__ void load_wstep(const float* __restrict__ wp, int s,
                                           float2* __restrict__ wb) {
    #pragma unroll
    for (int j = 0; j < 4; ++j)
        wb[j] = *(const float2*)(wp + (size_t)(s * 4 + j) * UNITS);
}

// per step: 8 rows x (8 add + 4 max3/min3) = 96 VALU inst
template<bool ISMAX>
__device__ __forceinline__ void compute_step(const float4* __restrict__ xb,
                                             const float2* __restrict__ wq,
                                             float2* __restrict__ acc) {
    #pragma unroll
    for (int r = 0; r < BR; ++r) {
        const float4 a = xb[r];
        const float t0x = a.x + wq[0].x, t0y = a.x + wq[0].y;
        const float t1x = a.y + wq[1].x, t1y = a.y + wq[1].y;
        const float t2x = a.z + wq[2].x, t2y = a.z + wq[2].y;
        const float t3x = a.w + wq[3].x, t3y = a.w + wq[3].y;
        float2 A = acc[r];
        if (ISMAX) {
            A.x = max3f(A.x, t0x, t1x);  A.x = max3f(A.x, t2x, t3x);
            A.y = max3f(A.y, t0y, t1y);  A.y = max3f(A.y, t2y, t3y);
        } else {
            A.x = min3f(A.x, t0x, t1x);  A.x = min3f(A.x, t2x, t3x);
            A.y = min3f(A.y, t0y, t1y);  A.y = min3f(A.y, t2y, t3y);
        }
        acc[r] = A;
    }
}

// software pipeline: x one step ahead (as R19); w TWO steps ahead via
// W0..W3 quad-buffer, loop unrolled x4 so every buffer name is static.
template<bool ISMAX>
__device__ __forceinline__ void main_loop(cfloat* __restrict__ xp,
                                          const float* __restrict__ wp,
                                          float2* __restrict__ acc) {
    float4 xA[BR], xB[BR];
    float2 W0[4], W1[4], W2[4], W3[4];
    load_xstep(xp, 0, xA);
    load_wstep(wp, 0, W0);
    load_wstep(wp, 1, W1);                    // 2 w-batches in flight
    #pragma unroll 1
    for (int s = 0; s < NS; s += 4) {
        load_xstep(xp, s + 1, xB);
        load_wstep(wp, s + 2, W2);            // dist-2: used 2 computes later
        compute_step<ISMAX>(xA, W0, acc);

        load_xstep(xp, s + 2, xA);
        load_wstep(wp, s + 3, W3);
        compute_step<ISMAX>(xB, W1, acc);

        load_xstep(xp, s + 3, xB);
        if (s + 4 < NS) load_wstep(wp, s + 4, W0);
        compute_step<ISMAX>(xA, W2, acc);

        if (s + 4 < NS) load_xstep(xp, s + 4, xA);
        if (s + 5 < NS) load_wstep(wp, s + 5, W1);
        compute_step<ISMAX>(xB, W3, acc);
    }
}

__global__ __launch_bounds__(1024)
__attribute__((amdgpu_waves_per_eu(4, 4)))
void tropical_kernel(const float* __restrict__ x,
                     const float* __restrict__ w,
                     float* __restrict__ out) {
    __shared__ float lds[LDSZ];   // 96KB declared (belt); 64KB used
    const int tid  = threadIdx.x;
    const int lane = tid & 63;
    const int wv   = __builtin_amdgcn_readfirstlane(tid >> 6);  // 0..15
    const int kslice = wv & 7;           // k origin index
    const int half   = wv >> 3;          // 0: max units 0-127, 1: min 128-255
    const int ks   = kslice * KW;
    const int u0   = lane * 2;           // 2 units per lane, contiguous
    const int row0 = blockIdx.x * BR;

    // x pointer in the constant address space (identical to R19)
    cfloat* xp = (cfloat*)(unsigned long long)(x + (size_t)row0 * FEAT + ks);
    const float* wp = w + (size_t)ks * UNITS + half * 128 + u0;

    float2 acc[BR];
    const float init = half ? __builtin_inff() : -__builtin_inff();
    #pragma unroll
    for (int r = 0; r < BR; ++r)
        acc[r] = make_float2(init, init);

    if (half == 0) main_loop<true >(xp, wp, acc);
    else           main_loop<false>(xp, wp, acc);

    // ---- partials to LDS: wave wv -> slot wv, 128 units of its half ----
    #pragma unroll
    for (int r = 0; r < BR; ++r)
        *(float2*)&lds[(wv * BR + r) * 128 + u0] = acc[r];   // 512B/wave-row
    __syncthreads();   // the kernel's only barrier

    // ---- combine 8 k-slice partials; thread -> float2 of output ----
    const int r  = tid >> 7;             // 0..7
    const int j2 = tid & 127;
    const int hh = j2 >> 6;              // wave-uniform: 0=max half, 1=min half
    const int uo = (j2 & 63) * 2;        // unit offset within the half
    float2 v = *(const float2*)&lds[((hh * 8 + 0) * BR + r) * 128 + uo];
    #pragma unroll
    for (int j = 1; j < 8; ++j) {
        const float2 p = *(const float2*)&lds[((hh * 8 + j) * BR + r) * 128 + uo];
        if (hh == 0) { v.x = fmaxf(v.x, p.x); v.y = fmaxf(v.y, p.y); }
        else         { v.x = fminf(v.x, p.x); v.y = fminf(v.y, p.y); }
    }
    *(float2*)&out[(size_t)(row0 + r) * UNITS + hh * 128 + uo] = v;
}

extern "C" void kernel_launch(void* const* d_in, const int* in_sizes, int n_in,
                              void* d_out, int out_size, void* d_ws, size_t ws_size,
                              hipStream_t stream) {
    const float* x = (const float*)d_in[0];   // (2048, 512)
    const float* w = (const float*)d_in[1];   // (512, 256)
    float* out = (float*)d_out;               // (2048, 256)

    // 256 blocks x 16 waves = 1 block/CU, 4 waves/SIMD (R19 geometry)
    tropical_kernel<<<dim3(2048 / BR), dim3(1024), 0, stream>>>(x, w, out);
}

// Round 12
// 67.662 us; speedup vs baseline: 1.0685x; 1.0572x over previous
//
#include <hip/hip_runtime.h>
#include <math.h>

// Tropical max/min-plus pseudo-matmul.
// out[b,u] = max_f(x[b,f] + w[f,u]) for u<128, min_f otherwise.
//
// R23 = R20 (forced-SMEM x, proven correct @69.0) + PACKED adds.
// Falsified so far: x-path (R12 LDS / R19 AS4 / R20 SMEM tie at 68-69),
// TLP 2->4 (+0.3), 2 blocks/CU (hurt: w L2 amplification), w-depth 2
// (hurt: VGPR edge + code bloat). Kernel pinned ~2x the 5.12us scalar
// VALU floor in ALL of them -> attack the floor itself.
// v_pk_add_f32 (VOP3P, gfx90a/gfx942 lineage): 2 adds/lane/cyc, full
// rate on CDNA (MI250X "95.7 TF packed FP32"). No packed max3, but max3
// already fuses 2 compares. Per (row, 4k, 2units): 4 pk_add + 4 max3 =
// 8 instr/16cyc vs scalar 12/24cyc -> VALU x0.67 (floor 5.12 -> 3.4us).
// x in SGPR pairs is exactly VOP3P's single-64b-scalar operand form:
//   s_load_dwordx2 -> (x_2k, x_2k+1); broadcast via op_sel:
//   lo: op_sel:[0,0] op_sel_hi:[0,1]  (both result lanes take lo(src0))
//   hi: op_sel:[1,0] op_sel_hi:[1,1]  (both take hi(src0))
//   src1 (w pair) keeps natural lo/hi. Zero duplication cost.
// SMEM OOO -> lgkmcnt(0) only; SB(0)/wait/SB(0) fences kept (rule #18:
// reg-only pk_add would hoist past a bare waitcnt). w stays VMEM f32x2
// dist-1 (dist-2 falsified in R22). Geometry = R20: 256 blocks x 16
// waves (8 kslices x 2 halves), KW=64, 2 units/lane, wave-half min/max
// (no divergence, no sign math), waves_per_eu(4,4), 96KB LDS belt.
// VGPR ~45 (w 2x8 + t 8 + acc 16 + addr), SGPR ~70 (x dbuf 2x16 + bases).

#define FEAT  512
#define UNITS 256
#define BR    8            // rows per block
#define NW    16           // waves per block (8 k-slices x 2 halves)
#define KW    64           // k per wave
#define NS    (KW / 4)     // 16 steps, 4 k per step
#define LDSZ  24576        // 96KB declared (occupancy belt); 64KB used

typedef float f32x2 __attribute__((ext_vector_type(2)));

__device__ __forceinline__ float max3f(float a, float b, float c) {
    return fmaxf(fmaxf(a, b), c);   // v_max3_f32
}
__device__ __forceinline__ float min3f(float a, float b, float c) {
    return fminf(fminf(a, b), c);   // v_min3_f32
}

// one s_load_dwordx2 at compile-time byte offset (template -> guaranteed imm)
template<int OFF>
__device__ __forceinline__ void sload2(const float* __restrict__ p, f32x2& d) {
    asm volatile("s_load_dwordx2 %0, %1, %2" : "=s"(d) : "s"(p), "i"(OFF));
}

// 16 s_load_dwordx2: x[row0+r][k0..k0+3] as 2 SGPR pairs/row (offsets r*2048)
__device__ __forceinline__ void sload_xstep(const float* __restrict__ xp_s,
                                            f32x2* __restrict__ xb) {
#define SL(r) sload2<(r)*2048>(xp_s, xb[2*(r)]); sload2<(r)*2048+8>(xp_s, xb[2*(r)+1]);
    SL(0) SL(1) SL(2) SL(3) SL(4) SL(5) SL(6) SL(7)
#undef SL
}

__device__ __forceinline__ void smem_wait_fenced() {
    __builtin_amdgcn_sched_barrier(0);                 // pin cover-compute above
    asm volatile("s_waitcnt lgkmcnt(0)" ::: "memory"); // SMEM is OOO: only 0 valid
    __builtin_amdgcn_sched_barrier(0);                 // pin consumers below
}

// packed add, src0 = SGPR pair, lo half broadcast to both result lanes
__device__ __forceinline__ f32x2 pk_add_lo(f32x2 xs, f32x2 wv) {
    f32x2 d;
    asm("v_pk_add_f32 %0, %1, %2 op_sel:[0,0] op_sel_hi:[0,1]"
        : "=v"(d) : "s"(xs), "v"(wv));
    return d;
}
// packed add, hi half of the SGPR pair broadcast to both result lanes
__device__ __forceinline__ f32x2 pk_add_hi(f32x2 xs, f32x2 wv) {
    f32x2 d;
    asm("v_pk_add_f32 %0, %1, %2 op_sel:[1,0] op_sel_hi:[1,1]"
        : "=v"(d) : "s"(xs), "v"(wv));
    return d;
}

// 4 dwordx2: w[k0+j][u0..u0+1] -- 64 lanes x 8B = 512B contiguous
__device__ __forceinline__ void load_wstep(const float* __restrict__ wp, int s,
                                           f32x2* __restrict__ wb) {
    #pragma unroll
    for (int j = 0; j < 4; ++j)
        wb[j] = *(const f32x2*)(wp + (size_t)(s * 4 + j) * UNITS);
}

// per step: 8 rows x (4 pk_add + 4 max3/min3) = 64 VALU inst (was 96)
template<bool ISMAX>
__device__ __forceinline__ void compute_step(const f32x2* __restrict__ xb,
                                             const f32x2* __restrict__ wq,
                                             f32x2* __restrict__ acc) {
    #pragma unroll
    for (int r = 0; r < BR; ++r) {
        const f32x2 t0 = pk_add_lo(xb[2 * r],     wq[0]);  // x[4s]   + w-row 4s
        const f32x2 t1 = pk_add_hi(xb[2 * r],     wq[1]);  // x[4s+1] + w-row 4s+1
        const f32x2 t2 = pk_add_lo(xb[2 * r + 1], wq[2]);  // x[4s+2] + w-row 4s+2
        const f32x2 t3 = pk_add_hi(xb[2 * r + 1], wq[3]);  // x[4s+3] + w-row 4s+3
        f32x2 A = acc[r];
        if (ISMAX) {
            A.x = max3f(A.x, t0.x, t1.x);  A.x = max3f(A.x, t2.x, t3.x);
            A.y = max3f(A.y, t0.y, t1.y);  A.y = max3f(A.y, t2.y, t3.y);
        } else {
            A.x = min3f(A.x, t0.x, t1.x);  A.x = min3f(A.x, t2.x, t3.x);
            A.y = min3f(A.y, t0.y, t1.y);  A.y = min3f(A.y, t2.y, t3.y);
        }
        acc[r] = A;
    }
}

// software pipeline: x (SMEM) and w (VMEM) one step ahead; one SMEM batch
// outstanding at each wait (R20 structure, proven correct)
template<bool ISMAX>
__device__ __forceinline__ void main_loop(const float* __restrict__ xp,
                                          const float* __restrict__ wp,
                                          f32x2* __restrict__ acc) {
    f32x2 xA[BR * 2], xB[BR * 2];
    f32x2 wA[4], wB[4];
    sload_xstep(xp, xA);
    load_wstep(wp, 0, wA);
    smem_wait_fenced();                       // batch 0 ready
    #pragma unroll 1
    for (int s = 0; s < NS; s += 2) {
        sload_xstep(xp + (s + 1) * 4, xB);    // issue batch s+1
        load_wstep(wp, s + 1, wB);
        compute_step<ISMAX>(xA, wA, acc);     // covers batch s+1 latency
        smem_wait_fenced();                   // batch s+1 ready
        if (s + 2 < NS) {
            sload_xstep(xp + (s + 2) * 4, xA);
            load_wstep(wp, s + 2, wA);
        }
        compute_step<ISMAX>(xB, wB, acc);     // covers batch s+2 latency
        smem_wait_fenced();                   // batch s+2 ready (tail: no-op)
    }
}

__global__ __launch_bounds__(1024)
__attribute__((amdgpu_waves_per_eu(4, 4)))
void tropical_kernel(const float* __restrict__ x,
                     const float* __restrict__ w,
                     float* __restrict__ out) {
    __shared__ float lds[LDSZ];   // 96KB declared (belt); 64KB used
    const int tid  = threadIdx.x;
    const int lane = tid & 63;
    const int wv   = __builtin_amdgcn_readfirstlane(tid >> 6);  // 0..15
    const int kslice = wv & 7;           // k origin index
    const int half   = wv >> 3;          // 0: max units 0-127, 1: min 128-255
    const int ks   = kslice * KW;
    const int u0   = lane * 2;           // 2 units per lane, contiguous
    const int row0 = blockIdx.x * BR;

    const float* xp = x + (size_t)row0 * FEAT + ks;          // uniform
    const float* wp = w + (size_t)ks * UNITS + half * 128 + u0;

    f32x2 acc[BR];
    const float init = half ? __builtin_inff() : -__builtin_inff();
    #pragma unroll
    for (int r = 0; r < BR; ++r)
        acc[r] = (f32x2){init, init};

    if (half == 0) main_loop<true >(xp, wp, acc);
    else           main_loop<false>(xp, wp, acc);

    // ---- partials to LDS: wave wv -> slot wv, 128 units of its half ----
    #pragma unroll
    for (int r = 0; r < BR; ++r)
        *(f32x2*)&lds[(wv * BR + r) * 128 + u0] = acc[r];   // 512B/wave-row
    __syncthreads();   // the kernel's only barrier

    // ---- combine 8 k-slice partials; thread -> float2 of output ----
    const int r  = tid >> 7;             // 0..7
    const int j2 = tid & 127;
    const int hh = j2 >> 6;              // wave-uniform: 0=max half, 1=min half
    const int uo = (j2 & 63) * 2;        // unit offset within the half
    f32x2 v = *(const f32x2*)&lds[((hh * 8 + 0) * BR + r) * 128 + uo];
    #pragma unroll
    for (int j = 1; j < 8; ++j) {
        const f32x2 p = *(const f32x2*)&lds[((hh * 8 + j) * BR + r) * 128 + uo];
        if (hh == 0) { v.x = fmaxf(v.x, p.x); v.y = fmaxf(v.y, p.y); }
        else         { v.x = fminf(v.x, p.x); v.y = fminf(v.y, p.y); }
    }
    *(f32x2*)&out[(size_t)(row0 + r) * UNITS + hh * 128 + uo] = v;
}

extern "C" void kernel_launch(void* const* d_in, const int* in_sizes, int n_in,
                              void* d_out, int out_size, void* d_ws, size_t ws_size,
                              hipStream_t stream) {
    const float* x = (const float*)d_in[0];   // (2048, 512)
    const float* w = (const float*)d_in[1];   // (512, 256)
    float* out = (float*)d_out;               // (2048, 256)

    // 256 blocks x 16 waves = 1 block/CU, 4 waves/SIMD (R20 geometry)
    tropical_kernel<<<dim3(2048 / BR), dim3(1024), 0, stream>>>(x, w, out);
}